// Round 10
// baseline (77.625 us; speedup 1.0000x reference)
//
#include <hip/hip_runtime.h>

typedef unsigned short u16;
typedef __attribute__((ext_vector_type(8))) __bf16 bf16x8;
typedef __attribute__((ext_vector_type(4))) float f32x4;
typedef __attribute__((ext_vector_type(8))) short short8;
typedef __attribute__((ext_vector_type(4))) u16 us4;
typedef __attribute__((ext_vector_type(4))) unsigned u32x4;

#define T_SEQ 1024
#define PW 1280   // P row: Q(512) K(512) QML(128) KML(128); V lives in Vtb
#define QSC 0.18033688f   // 0.125 * log2(e): folded into Q at projection
#define L2E 1.4426950408889634f

__device__ __forceinline__ u16 f2bf(float f) {
  unsigned u = __float_as_uint(f);
  u += 0x7fff + ((u >> 16) & 1);
  return (u16)(u >> 16);
}
__device__ __forceinline__ float bf2f(u16 v) {
  return __uint_as_float((unsigned)v << 16);
}

// exact per-qtile kv-tile occupancy masks (verified rounds 2-9)
__constant__ u16 GLOB_M[16] = {0x0101,0x0303,0x0707,0x0F0F,0x1F1F,0x3F3F,0x7F7F,0xFFFF,
                               0xFFFF,0x0307,0x070F,0x0F1F,0x1F3F,0x3F7F,0x7FFF,0xFFFF};
__constant__ u16 LOC_M[16]  = {0x0101,0x0303,0x0607,0x0C0D,0x1819,0x3031,0x6061,0xC0C1,
                               0x8183,0x0307,0x060F,0x0C1D,0x1839,0x3071,0x60E1,0xC1C1};

__device__ __forceinline__ void gll16(const u16* gp, u16* lp) {
  __builtin_amdgcn_global_load_lds((const __attribute__((address_space(1))) unsigned*)gp,
                                   (__attribute__((address_space(3))) unsigned*)lp, 16, 0, 0);
}

// 256-thread stage: NISS*32 rows x 64 cols, linear LDS dest, inv-swizzled src
template<int NISS>
__device__ __forceinline__ void stage_sw(u16* lds, const u16* __restrict__ g,
                                         int ld, int tid) {
  const int w = tid >> 6;
#pragma unroll
  for (int i = 0; i < NISS; ++i) {
    int row = i * 32 + (tid >> 3);
    int cswz = ((tid & 7) << 4) ^ ((row & 7) << 4);
    gll16(g + (size_t)row * ld + (cswz >> 1), lds + i * 2048 + w * 512);
  }
}

// 512-thread stage: full 64x64 bf16 tile in ONE gll instr per thread
__device__ __forceinline__ void stage8(u16* lds, const u16* __restrict__ g,
                                       int ld, int tid) {
  int row = tid >> 3;
  int cswz = (((tid & 7) << 4) ^ ((row & 7) << 4)) >> 1;   // u16 units
  gll16(g + (size_t)row * ld + cswz, lds + (tid >> 6) * 512);
}

// read bf16x8 fragment at logical (row, colbyte) from a swizzled 64-col tile
__device__ __forceinline__ bf16x8 rd_sw(const u16* lds, int row, int colbyte) {
  return *(const bf16x8*)&lds[row * 64 + ((colbyte ^ ((row & 7) << 4)) >> 1)];
}

__global__ void prep_all(const float4* __restrict__ x, u16* __restrict__ xb,
                         const float* __restrict__ Wq, const float* __restrict__ Wk,
                         const float* __restrict__ Wv, const float* __restrict__ Wqml,
                         const float* __restrict__ Wkml, const float* __restrict__ Wp,
                         const float* __restrict__ bq, const float* __restrict__ bk,
                         const float* __restrict__ bv, const float* __restrict__ bqml,
                         const float* __restrict__ bkml,
                         u16* __restrict__ Wcat, u16* __restrict__ Wpx, float* __restrict__ bcat) {
  if (blockIdx.x < 2048) {
    int i = blockIdx.x * 256 + threadIdx.x;
    float4 v = x[i];
    us4 o = { f2bf(v.x), f2bf(v.y), f2bf(v.z), f2bf(v.w) };
    *(us4*)&xb[i * 4] = o;
    return;
  }
  int idx = (blockIdx.x - 2048) * 256 + threadIdx.x;
  const int NW = 1792 * 512;
  if (idx < NW) {
    int row = idx >> 9;
    float v;
    if (row < 512)       v = Wq[idx];
    else if (row < 1024) v = Wk[idx - 512 * 512];
    else if (row < 1536) v = Wv[idx - 1024 * 512];
    else if (row < 1664) v = Wqml[idx - 1536 * 512];
    else                 v = Wkml[idx - 1664 * 512];
    Wcat[idx] = f2bf(v);
    return;
  }
  int i2 = idx - NW;
  if (i2 < 512 * 640) {
    int n = i2 / 640, k2 = i2 - n * 640;
    float v = (k2 < 512) ? Wp[n * 512 + k2] : Wp[n * 512 + k2 - 384];
    Wpx[i2] = f2bf(v);
    return;
  }
  int i3 = i2 - 512 * 640;
  if (i3 < 1792) {
    float v;
    if (i3 < 512)       v = bq[i3];
    else if (i3 < 1024) v = bk[i3 - 512];
    else if (i3 < 1536) v = bv[i3 - 1024];
    else if (i3 < 1664) v = bqml[i3 - 1536];
    else                v = bkml[i3 - 1664];
    bcat[i3] = v;
  }
}

// ---------------- 128x128 QKV projection GEMM, BK=64, swizzled ----------------
// Q and QML output columns pre-scaled by 0.125*log2e (attn works in exp2 domain).
__global__ __launch_bounds__(256) void gemm_qkv(
    const u16* __restrict__ A, const u16* __restrict__ Bw,
    const float* __restrict__ bias, u16* __restrict__ Pout, u16* __restrict__ Vtb) {
  __shared__ u16 As[2][8192];
  __shared__ u16 Bs[2][8192];
  const int tid = threadIdx.x;
  const int lane = tid & 63, w = tid >> 6;
  const int g = lane >> 4, c = lane & 15;
  const int n0 = blockIdx.x * 128, m0 = blockIdx.y * 128;
  const int wm = (w >> 1) * 64, wn = (w & 1) * 64;

  f32x4 acc[4][4] = {};
  stage_sw<4>(As[0], A + (size_t)m0 * 512, 512, tid);
  stage_sw<4>(Bs[0], Bw + (size_t)n0 * 512, 512, tid);
  __syncthreads();
  for (int ks = 0; ks < 8; ++ks) {
    int cur = ks & 1;
    if (ks + 1 < 8) {
      stage_sw<4>(As[cur ^ 1], A + (size_t)m0 * 512 + (ks + 1) * 64, 512, tid);
      stage_sw<4>(Bs[cur ^ 1], Bw + (size_t)n0 * 512 + (ks + 1) * 64, 512, tid);
    }
#pragma unroll
    for (int h = 0; h < 2; ++h) {
      bf16x8 av[4], bv[4];
#pragma unroll
      for (int f = 0; f < 4; ++f) {
        av[f] = rd_sw(As[cur], wm + f * 16 + c, h * 64 + g * 16);
        bv[f] = rd_sw(Bs[cur], wn + f * 16 + c, h * 64 + g * 16);
      }
#pragma unroll
      for (int fm = 0; fm < 4; ++fm)
#pragma unroll
        for (int fn = 0; fn < 4; ++fn)
          acc[fm][fn] = __builtin_amdgcn_mfma_f32_16x16x32_bf16(av[fm], bv[fn], acc[fm][fn], 0, 0, 0);
    }
    __syncthreads();
  }

  const bool isV = (n0 >= 1024 && n0 < 1536);
#pragma unroll
  for (int fm = 0; fm < 4; ++fm)
#pragma unroll
    for (int fn = 0; fn < 4; ++fn) {
      int row = m0 + wm + fm * 16 + g * 4;
      int col = n0 + wn + fn * 16 + c;
      float bb = bias[col];
      if (isV) {
        int d = col - 1024;
        int bidx = row >> 10, t = row & 1023;
        us4 pack = { f2bf(acc[fm][fn][0] + bb), f2bf(acc[fm][fn][1] + bb),
                     f2bf(acc[fm][fn][2] + bb), f2bf(acc[fm][fn][3] + bb) };
        *(us4*)&Vtb[((size_t)bidx * 512 + d) * 1024 + t] = pack;
      } else {
        float sc = (col < 512 || (col >= 1536 && col < 1664)) ? QSC : 1.0f;
        int pcol = (col < 1024) ? col : col - 512;
#pragma unroll
        for (int r = 0; r < 4; ++r)
          Pout[(size_t)(row + r) * PW + pcol] = f2bf((acc[fm][fn][r] + bb) * sc);
      }
    }
}

// ---------------- output projection: 128x64 tiles, K=640, swizzled ----------------
__global__ __launch_bounds__(256) void gemm_out(
    const u16* __restrict__ A, const u16* __restrict__ Bw,
    const float* __restrict__ bias, float* __restrict__ Cout) {
  __shared__ u16 As[2][8192];
  __shared__ u16 Bs[2][4096];
  const int tid = threadIdx.x;
  const int lane = tid & 63, w = tid >> 6;
  const int g = lane >> 4, c = lane & 15;
  const int n0 = blockIdx.x * 64, m0 = blockIdx.y * 128;
  const int wm = (w >> 1) * 64, wn = (w & 1) * 32;

  f32x4 acc[4][2] = {};
  stage_sw<4>(As[0], A + (size_t)m0 * 640, 640, tid);
  stage_sw<2>(Bs[0], Bw + (size_t)n0 * 640, 640, tid);
  __syncthreads();
  for (int ks = 0; ks < 10; ++ks) {
    int cur = ks & 1;
    if (ks + 1 < 10) {
      stage_sw<4>(As[cur ^ 1], A + (size_t)m0 * 640 + (ks + 1) * 64, 640, tid);
      stage_sw<2>(Bs[cur ^ 1], Bw + (size_t)n0 * 640 + (ks + 1) * 64, 640, tid);
    }
#pragma unroll
    for (int h = 0; h < 2; ++h) {
      bf16x8 av[4], bv[2];
#pragma unroll
      for (int f = 0; f < 4; ++f)
        av[f] = rd_sw(As[cur], wm + f * 16 + c, h * 64 + g * 16);
#pragma unroll
      for (int f = 0; f < 2; ++f)
        bv[f] = rd_sw(Bs[cur], wn + f * 16 + c, h * 64 + g * 16);
#pragma unroll
      for (int fm = 0; fm < 4; ++fm)
#pragma unroll
        for (int fn = 0; fn < 2; ++fn)
          acc[fm][fn] = __builtin_amdgcn_mfma_f32_16x16x32_bf16(av[fm], bv[fn], acc[fm][fn], 0, 0, 0);
    }
    __syncthreads();
  }
#pragma unroll
  for (int fm = 0; fm < 4; ++fm)
#pragma unroll
    for (int fn = 0; fn < 2; ++fn)
#pragma unroll
      for (int r = 0; r < 4; ++r) {
        int row = m0 + wm + fm * 16 + g * 4 + r;
        int col = n0 + wn + fn * 16 + c;
        Cout[(size_t)row * 512 + col] = acc[fm][fn][r] + bias[col];
      }
}

// ---------------- attention: tiles preloaded, per-tile counted vmcnt ----------
// grid (8 qt2, 32 units, 4 b); block owns 128 q-rows; every unit has <=4 kv-tiles.
//  u 0..23 : causal heads 2..7, 4-way split over kv-tiles (kt%4)
//  u 24..27: local heads 0,1, 2-way split (kt parity)
//  u 28..31: ml passes 0,1, 2-way split
__global__ __launch_bounds__(512, 4) void attn_k(
    const u16* __restrict__ P, const u16* __restrict__ Vtb,
    u16* __restrict__ Part_o, float* __restrict__ Part_ml,
    const float* __restrict__ bias_clip, const float* __restrict__ bias_clip_ml) {
  __shared__ u16 Ks[4][4096];   // up to 4 K tiles  [k][d]  (swizzled), 8 KB each
  __shared__ u16 Vs[4][4096];   // up to 4 V^T tiles [d][k] (swizzled), 8 KB each
  const int tid = threadIdx.x, lane = tid & 63, w = tid >> 6;
  const int g = lane >> 4, c = lane & 15;
  const int qt2 = blockIdx.x, u = blockIdx.y, b = blockIdx.z;

  int qcol, kcol, vsel;
  bool localMask;
  float kbias;
  unsigned mask;
  unsigned uni = (unsigned)LOC_M[2 * qt2] | (unsigned)LOC_M[2 * qt2 + 1];
  if (u < 24) {
    int h = 2 + (u >> 2), sp = u & 3;
    qcol = h * 64; kcol = 512 + h * 64; vsel = h; kbias = bias_clip[h];
    localMask = false;
    mask = ((unsigned)GLOB_M[2 * qt2] | (unsigned)GLOB_M[2 * qt2 + 1]) & (0x1111u << sp);
  } else if (u < 28) {
    int h = (u - 24) >> 1, sp = (u - 24) & 1;
    qcol = h * 64; kcol = 512 + h * 64; vsel = h; kbias = bias_clip[h];
    localMask = true;
    mask = uni & (sp ? 0xAAAAu : 0x5555u);
  } else {
    int mh = (u - 28) >> 1, sp = (u - 28) & 1;
    qcol = 1024 + mh * 64; kcol = 1152 + mh * 64; vsel = 2 + mh; kbias = bias_clip_ml[mh];
    localMask = true;
    mask = uni & (sp ? 0xAAAAu : 0x5555u);
  }
  kbias *= L2E;   // exp2 domain
  const size_t baseP = (size_t)b * T_SEQ * PW;
  const u16* __restrict__ Kbase = P + baseP + kcol;
  const u16* __restrict__ Vbase = Vtb + ((size_t)b * 512 + vsel * 64) * 1024;
  const int r0 = qt2 * 128 + w * 16;
  const int qg = r0 + c;                     // this lane's q row (global)

  // per-lane visibility bounds (verified R6-R9)
  int tq = (qg < 2) ? 0 : ((qg < 513) ? 2 * qg - 3 : 2 * qg - 1024);
  int upmax = (tq - 1) >> 1;
  int lomax = (tq - 2) >> 1;
  int wmin = (localMask && qg >= 2) ? ((qg < 513 ? qg - 2 : qg - 513) - 3) : -1000000;

  float mM = -1e8f, lL = 0.0f;
  f32x4 o[4] = {};

  if (mask) {
    // Q loads issued FIRST (oldest in vmcnt order: 2 outstanding before pairs)
    bf16x8 aq0 = *(const bf16x8*)&P[baseP + (size_t)qg * PW + qcol + g * 8];
    bf16x8 aq1 = *(const bf16x8*)&P[baseP + (size_t)qg * PW + qcol + 32 + g * 8];

    const int nt = __popc(mask);
    int kts[4] = {0, 0, 0, 0};
    unsigned rem = mask;
#pragma unroll
    for (int j = 0; j < 4; ++j) {
      if (j < nt) {
        int kt = __ffs(rem) - 1; rem &= rem - 1;
        kts[j] = kt;
        stage8(Ks[j], Kbase + (size_t)(kt * 64) * PW, PW, tid);
        stage8(Vs[j], Vbase + kt * 64, 1024, tid);
      }
    }

#pragma unroll
    for (int j = 0; j < 4; ++j) {
      if (j >= nt) break;
      // counted wait: own Q(2) + pairs <= j have landed (oldest-first vmcnt);
      // remaining pairs stay in flight under this tile's compute.
      {
        int left = nt - 1 - j;
        if (left == 0)      asm volatile("s_waitcnt vmcnt(0)" ::: "memory");
        else if (left == 1) asm volatile("s_waitcnt vmcnt(2)" ::: "memory");
        else if (left == 2) asm volatile("s_waitcnt vmcnt(4)" ::: "memory");
        else                asm volatile("s_waitcnt vmcnt(6)" ::: "memory");
      }
      __builtin_amdgcn_sched_barrier(0);
      __builtin_amdgcn_s_barrier();          // all waves: tile j staged

      const int k0 = kts[j] * 64;

      // QK^T swapped (Q pre-scaled): S^T[k][q]; lane (g,c): q=c, k=k0+cb*16+g*4+r
      float s[4][4];
#pragma unroll
      for (int cb = 0; cb < 4; ++cb) {
        f32x4 accs = {};
        bf16x8 bk0 = rd_sw(Ks[j], cb * 16 + c, g * 16);
        bf16x8 bk1 = rd_sw(Ks[j], cb * 16 + c, 64 + g * 16);
        accs = __builtin_amdgcn_mfma_f32_16x16x32_bf16(bk0, aq0, accs, 0, 0, 0);
        accs = __builtin_amdgcn_mfma_f32_16x16x32_bf16(bk1, aq1, accs, 0, 0, 0);
#pragma unroll
        for (int r = 0; r < 4; ++r) s[cb][r] = accs[r];
      }

      // mask + clip bias (per-lane scalar bounds, log2 domain)
#pragma unroll
      for (int cb = 0; cb < 4; ++cb) {
        int kb = k0 + cb * 16 + g * 4;
#pragma unroll
        for (int r = 0; r < 4; ++r) {
          int kk = kb + r;
          bool tok = kk < 2;
          bool low = kk >= 513;
          int jk = kk - (low ? 513 : 2);
          int bnd = low ? lomax : upmax;
          bool vis = tok | ((jk <= bnd) & (jk >= wmin));
          float addb = (kk == 1) ? kbias : 0.0f;
          s[cb][r] = vis ? (s[cb][r] + addb) : -1e9f;
        }
      }

      // per-lane online softmax (exp2)
      float rmax = s[0][0];
#pragma unroll
      for (int cb = 0; cb < 4; ++cb)
#pragma unroll
        for (int r = 0; r < 4; ++r) rmax = fmaxf(rmax, s[cb][r]);
      rmax = fmaxf(rmax, __shfl_xor(rmax, 16));
      rmax = fmaxf(rmax, __shfl_xor(rmax, 32));
      float mnew = fmaxf(mM, rmax);
      float fr = exp2f(mM - mnew);
      float psum = 0.0f;
#pragma unroll
      for (int cb = 0; cb < 4; ++cb)
#pragma unroll
        for (int r = 0; r < 4; ++r) {
          float p = exp2f(s[cb][r] - mnew);
          s[cb][r] = p;
          psum += p;
        }
      psum += __shfl_xor(psum, 16);
      psum += __shfl_xor(psum, 32);
      lL = lL * fr + psum;
      mM = mnew;
#pragma unroll
      for (int db = 0; db < 4; ++db) o[db] *= fr;

      // in-register P -> B-fragment redistribution (validated R8/R9)
      unsigned wpk[4][2];
#pragma unroll
      for (int cb = 0; cb < 4; ++cb) {
        asm("v_cvt_pk_bf16_f32 %0, %1, %2" : "=v"(wpk[cb][0]) : "v"(s[cb][0]), "v"(s[cb][1]));
        asm("v_cvt_pk_bf16_f32 %0, %1, %2" : "=v"(wpk[cb][1]) : "v"(s[cb][2]), "v"(s[cb][3]));
      }
#pragma unroll
      for (int ks2 = 0; ks2 < 2; ++ks2) {
        unsigned tw[4];
#pragma unroll
        for (int rr = 0; rr < 2; ++rr) {
          unsigned L = wpk[2 * ks2][rr], H = wpk[2 * ks2 + 1][rr];
          unsigned sA = (g & 1) ? L : H;     // push for xor16 & xor32
          unsigned sB = (g & 1) ? H : L;     // push for xor48
          unsigned X16 = (unsigned)__shfl_xor((int)sA, 16);
          unsigned X32 = (unsigned)__shfl_xor((int)sA, 32);
          unsigned X48 = (unsigned)__shfl_xor((int)sB, 48);
          unsigned a  = (g >= 2) ? ((g == 3) ? X16 : X32) : ((g == 1) ? X48 : L);
          unsigned b2 = (g >= 2) ? ((g == 3) ? H : X48) : ((g == 1) ? X32 : X16);
          tw[rr] = a; tw[2 + rr] = b2;
        }
        u32x4 tw4 = { tw[0], tw[1], tw[2], tw[3] };
        bf16x8 ap = __builtin_bit_cast(bf16x8, tw4);
#pragma unroll
        for (int db = 0; db < 4; ++db) {
          bf16x8 av = rd_sw(Vs[j], db * 16 + c, ks2 * 64 + g * 16);
          o[db] = __builtin_amdgcn_mfma_f32_16x16x32_bf16(av, ap, o[db], 0, 0, 0);
        }
      }
    }
  }

  // epilogue: lane holds q = qg; o[db][r] = O[q][d = db*16 + g*4 + r]
  u16* po = Part_o + ((size_t)(u * 4 + b)) * T_SEQ * 64;
#pragma unroll
  for (int db = 0; db < 4; ++db) {
    us4 pk = { f2bf(o[db][0]), f2bf(o[db][1]), f2bf(o[db][2]), f2bf(o[db][3]) };
    *(us4*)&po[(size_t)qg * 64 + db * 16 + g * 4] = pk;
  }
  if (g == 0) {
    float2 ml = { mM, lL };
    *(float2*)&Part_ml[(((size_t)(u * 4 + b)) * T_SEQ + qg) * 2] = ml;
  }
}

// combine split partials -> Y (bf16, 640 cols).
__global__ __launch_bounds__(256) void combine_k(
    const u16* __restrict__ Part_o, const float* __restrict__ Part_ml,
    u16* __restrict__ Y, const float* __restrict__ mix_w) {
  int idx = blockIdx.x * 256 + threadIdx.x;  // 10*4*1024*16
  int q4 = idx & 15;
  int row = (idx >> 4) & 1023;
  int bb = (idx >> 14) & 3;
  int j = idx >> 16;
  int ns, bs, outcol;
  float wgt;
  if (j < 6)      { ns = 4; bs = j * 4;            outcol = 128 + j * 64;       wgt = (j < 2) ? mix_w[2 * j] : 1.0f; }
  else if (j < 8) { ns = 2; bs = 24 + (j - 6) * 2; outcol = (j - 6) * 64;       wgt = 1.0f; }
  else            { ns = 2; bs = 28 + (j - 8) * 2; outcol = 512 + (j - 8) * 64; wgt = mix_w[(j - 8) * 2 + 1]; }

  float mv[4], lv[4];
  float ms = -1e30f;
  for (int s = 0; s < ns; ++s) {
    size_t base = (((size_t)(bs + s) * 4 + bb) * 1024 + row) * 2;
    mv[s] = Part_ml[base];
    lv[s] = Part_ml[base + 1];
    ms = fmaxf(ms, mv[s]);
  }
  float denom = 0.0f, e[4];
  for (int s = 0; s < ns; ++s) { e[s] = exp2f(mv[s] - ms); denom += lv[s] * e[s]; }
  float inv = wgt / denom;
  float out[4] = {0.f, 0.f, 0.f, 0.f};
  for (int s = 0; s < ns; ++s) {
    us4 ov = *(const us4*)&Part_o[(((size_t)(bs + s) * 4 + bb) * 1024 + row) * 64 + q4 * 4];
#pragma unroll
    for (int t = 0; t < 4; ++t) out[t] += e[s] * bf2f(ov[t]);
  }
  us4 pk = { f2bf(out[0] * inv), f2bf(out[1] * inv), f2bf(out[2] * inv), f2bf(out[3] * inv) };
  *(us4*)&Y[((size_t)bb * 1024 + row) * 640 + outcol + q4 * 4] = pk;
}

extern "C" void kernel_launch(void* const* d_in, const int* in_sizes, int n_in,
                              void* d_out, int out_size, void* d_ws, size_t ws_size,
                              hipStream_t stream) {
  const float* x     = (const float*)d_in[0];
  const float* Wq    = (const float*)d_in[2];
  const float* bq    = (const float*)d_in[3];
  const float* Wk    = (const float*)d_in[4];
  const float* bk    = (const float*)d_in[5];
  const float* Wv    = (const float*)d_in[6];
  const float* bv    = (const float*)d_in[7];
  const float* Wqml  = (const float*)d_in[8];
  const float* bqml  = (const float*)d_in[9];
  const float* Wkml  = (const float*)d_in[10];
  const float* bkml  = (const float*)d_in[11];
  const float* mixw  = (const float*)d_in[12];
  const float* Wp    = (const float*)d_in[13];
  const float* bp    = (const float*)d_in[14];
  const float* bclip = (const float*)d_in[15];
  const float* bclipml = (const float*)d_in[16];

  u16* xb   = (u16*)d_ws;                  // 4096*512
  u16* Wcat = xb + 4096 * 512;             // 1792*512
  u16* Wpx  = Wcat + 1792 * 512;           // 512*640
  u16* Ybuf = Wpx + 512 * 640;             // 4096*640
  u16* Vtb  = Ybuf + 4096 * 640;           // 4*512*1024
  u16* Pbuf = Vtb + 4 * 512 * 1024;        // 4096*1280
  float* bcat = (float*)(Pbuf + 4096 * 1280);  // 2048 f32
  u16* Part_o = (u16*)(bcat + 2048);       // 32*4*1024*64 bf16 = 16.8 MB
  float* Part_ml = (float*)(Part_o + 32 * 4 * 1024 * 64);  // 32*4*1024*2 f32

  prep_all<<<6919, 256, 0, stream>>>((const float4*)x, xb, Wq, Wk, Wv, Wqml, Wkml, Wp,
                                     bq, bk, bv, bqml, bkml, Wcat, Wpx, bcat);
  gemm_qkv<<<dim3(14, 32), 256, 0, stream>>>(xb, Wcat, bcat, Pbuf, Vtb);
  attn_k<<<dim3(8, 32, 4), 512, 0, stream>>>(Pbuf, Vtb, Part_o, Part_ml, bclip, bclipml);
  combine_k<<<2560, 256, 0, stream>>>(Part_o, Part_ml, Ybuf, mixw);
  gemm_out<<<dim3(8, 32), 256, 0, stream>>>(Ybuf, Wpx, bp, (float*)d_out);
}

// Round 11
// 76.971 us; speedup vs baseline: 1.0085x; 1.0085x over previous
//
#include <hip/hip_runtime.h>

typedef unsigned short u16;
typedef __attribute__((ext_vector_type(8))) __bf16 bf16x8;
typedef __attribute__((ext_vector_type(4))) float f32x4;
typedef __attribute__((ext_vector_type(8))) short short8;
typedef __attribute__((ext_vector_type(4))) u16 us4;
typedef __attribute__((ext_vector_type(4))) unsigned u32x4;

#define T_SEQ 1024
#define PW 1280   // P row: Q(512) K(512) QML(128) KML(128); V lives in Vtb
#define QSC 0.18033688f   // 0.125 * log2(e): folded into Q at projection
#define L2E 1.4426950408889634f

__device__ __forceinline__ u16 f2bf(float f) {
  unsigned u = __float_as_uint(f);
  u += 0x7fff + ((u >> 16) & 1);
  return (u16)(u >> 16);
}
__device__ __forceinline__ float bf2f(u16 v) {
  return __uint_as_float((unsigned)v << 16);
}

// exact per-qtile kv-tile occupancy masks (verified rounds 2-10)
__constant__ u16 GLOB_M[16] = {0x0101,0x0303,0x0707,0x0F0F,0x1F1F,0x3F3F,0x7F7F,0xFFFF,
                               0xFFFF,0x0307,0x070F,0x0F1F,0x1F3F,0x3F7F,0x7FFF,0xFFFF};
__constant__ u16 LOC_M[16]  = {0x0101,0x0303,0x0607,0x0C0D,0x1819,0x3031,0x6061,0xC0C1,
                               0x8183,0x0307,0x060F,0x0C1D,0x1839,0x3071,0x60E1,0xC1C1};

__device__ __forceinline__ void gll16(const u16* gp, u16* lp) {
  __builtin_amdgcn_global_load_lds((const __attribute__((address_space(1))) unsigned*)gp,
                                   (__attribute__((address_space(3))) unsigned*)lp, 16, 0, 0);
}

// 256-thread stage: NISS*32 rows x 64 cols, linear LDS dest, inv-swizzled src
template<int NISS>
__device__ __forceinline__ void stage_sw(u16* lds, const u16* __restrict__ g,
                                         int ld, int tid) {
  const int w = tid >> 6;
#pragma unroll
  for (int i = 0; i < NISS; ++i) {
    int row = i * 32 + (tid >> 3);
    int cswz = ((tid & 7) << 4) ^ ((row & 7) << 4);
    gll16(g + (size_t)row * ld + (cswz >> 1), lds + i * 2048 + w * 512);
  }
}

// 512-thread stage: full 64x64 bf16 tile in ONE gll instr per thread
__device__ __forceinline__ void stage8(u16* lds, const u16* __restrict__ g,
                                       int ld, int tid) {
  int row = tid >> 3;
  int cswz = (((tid & 7) << 4) ^ ((row & 7) << 4)) >> 1;   // u16 units
  gll16(g + (size_t)row * ld + cswz, lds + (tid >> 6) * 512);
}

// read bf16x8 fragment at logical (row, colbyte) from a swizzled 64-col tile
__device__ __forceinline__ bf16x8 rd_sw(const u16* lds, int row, int colbyte) {
  return *(const bf16x8*)&lds[row * 64 + ((colbyte ^ ((row & 7) << 4)) >> 1)];
}

__global__ void prep_all(const float4* __restrict__ x, u16* __restrict__ xb,
                         const float* __restrict__ Wq, const float* __restrict__ Wk,
                         const float* __restrict__ Wv, const float* __restrict__ Wqml,
                         const float* __restrict__ Wkml, const float* __restrict__ Wp,
                         const float* __restrict__ bq, const float* __restrict__ bk,
                         const float* __restrict__ bv, const float* __restrict__ bqml,
                         const float* __restrict__ bkml,
                         u16* __restrict__ Wcat, u16* __restrict__ Wpx, float* __restrict__ bcat) {
  if (blockIdx.x < 2048) {
    int i = blockIdx.x * 256 + threadIdx.x;
    float4 v = x[i];
    us4 o = { f2bf(v.x), f2bf(v.y), f2bf(v.z), f2bf(v.w) };
    *(us4*)&xb[i * 4] = o;
    return;
  }
  int idx = (blockIdx.x - 2048) * 256 + threadIdx.x;
  const int NW = 1792 * 512;
  if (idx < NW) {
    int row = idx >> 9;
    float v;
    if (row < 512)       v = Wq[idx];
    else if (row < 1024) v = Wk[idx - 512 * 512];
    else if (row < 1536) v = Wv[idx - 1024 * 512];
    else if (row < 1664) v = Wqml[idx - 1536 * 512];
    else                 v = Wkml[idx - 1664 * 512];
    Wcat[idx] = f2bf(v);
    return;
  }
  int i2 = idx - NW;
  if (i2 < 512 * 640) {
    int n = i2 / 640, k2 = i2 - n * 640;
    float v = (k2 < 512) ? Wp[n * 512 + k2] : Wp[n * 512 + k2 - 384];
    Wpx[i2] = f2bf(v);
    return;
  }
  int i3 = i2 - 512 * 640;
  if (i3 < 1792) {
    float v;
    if (i3 < 512)       v = bq[i3];
    else if (i3 < 1024) v = bk[i3 - 512];
    else if (i3 < 1536) v = bv[i3 - 1024];
    else if (i3 < 1664) v = bqml[i3 - 1536];
    else                v = bkml[i3 - 1664];
    bcat[i3] = v;
  }
}

// ---------------- 128x128 QKV projection GEMM, BK=64, swizzled ----------------
// Q and QML output columns pre-scaled by 0.125*log2e (attn works in exp2 domain).
__global__ __launch_bounds__(256) void gemm_qkv(
    const u16* __restrict__ A, const u16* __restrict__ Bw,
    const float* __restrict__ bias, u16* __restrict__ Pout, u16* __restrict__ Vtb) {
  __shared__ u16 As[2][8192];
  __shared__ u16 Bs[2][8192];
  const int tid = threadIdx.x;
  const int lane = tid & 63, w = tid >> 6;
  const int g = lane >> 4, c = lane & 15;
  const int n0 = blockIdx.x * 128, m0 = blockIdx.y * 128;
  const int wm = (w >> 1) * 64, wn = (w & 1) * 64;

  f32x4 acc[4][4] = {};
  stage_sw<4>(As[0], A + (size_t)m0 * 512, 512, tid);
  stage_sw<4>(Bs[0], Bw + (size_t)n0 * 512, 512, tid);
  __syncthreads();
  for (int ks = 0; ks < 8; ++ks) {
    int cur = ks & 1;
    if (ks + 1 < 8) {
      stage_sw<4>(As[cur ^ 1], A + (size_t)m0 * 512 + (ks + 1) * 64, 512, tid);
      stage_sw<4>(Bs[cur ^ 1], Bw + (size_t)n0 * 512 + (ks + 1) * 64, 512, tid);
    }
#pragma unroll
    for (int h = 0; h < 2; ++h) {
      bf16x8 av[4], bv[4];
#pragma unroll
      for (int f = 0; f < 4; ++f) {
        av[f] = rd_sw(As[cur], wm + f * 16 + c, h * 64 + g * 16);
        bv[f] = rd_sw(Bs[cur], wn + f * 16 + c, h * 64 + g * 16);
      }
#pragma unroll
      for (int fm = 0; fm < 4; ++fm)
#pragma unroll
        for (int fn = 0; fn < 4; ++fn)
          acc[fm][fn] = __builtin_amdgcn_mfma_f32_16x16x32_bf16(av[fm], bv[fn], acc[fm][fn], 0, 0, 0);
    }
    __syncthreads();
  }

  const bool isV = (n0 >= 1024 && n0 < 1536);
#pragma unroll
  for (int fm = 0; fm < 4; ++fm)
#pragma unroll
    for (int fn = 0; fn < 4; ++fn) {
      int row = m0 + wm + fm * 16 + g * 4;
      int col = n0 + wn + fn * 16 + c;
      float bb = bias[col];
      if (isV) {
        int d = col - 1024;
        int bidx = row >> 10, t = row & 1023;
        us4 pack = { f2bf(acc[fm][fn][0] + bb), f2bf(acc[fm][fn][1] + bb),
                     f2bf(acc[fm][fn][2] + bb), f2bf(acc[fm][fn][3] + bb) };
        *(us4*)&Vtb[((size_t)bidx * 512 + d) * 1024 + t] = pack;
      } else {
        float sc = (col < 512 || (col >= 1536 && col < 1664)) ? QSC : 1.0f;
        int pcol = (col < 1024) ? col : col - 512;
#pragma unroll
        for (int r = 0; r < 4; ++r)
          Pout[(size_t)(row + r) * PW + pcol] = f2bf((acc[fm][fn][r] + bb) * sc);
      }
    }
}

// ---------------- output projection: 128x64 tiles, K=640, swizzled ----------------
__global__ __launch_bounds__(256) void gemm_out(
    const u16* __restrict__ A, const u16* __restrict__ Bw,
    const float* __restrict__ bias, float* __restrict__ Cout) {
  __shared__ u16 As[2][8192];
  __shared__ u16 Bs[2][4096];
  const int tid = threadIdx.x;
  const int lane = tid & 63, w = tid >> 6;
  const int g = lane >> 4, c = lane & 15;
  const int n0 = blockIdx.x * 64, m0 = blockIdx.y * 128;
  const int wm = (w >> 1) * 64, wn = (w & 1) * 32;

  f32x4 acc[4][2] = {};
  stage_sw<4>(As[0], A + (size_t)m0 * 640, 640, tid);
  stage_sw<2>(Bs[0], Bw + (size_t)n0 * 640, 640, tid);
  __syncthreads();
  for (int ks = 0; ks < 10; ++ks) {
    int cur = ks & 1;
    if (ks + 1 < 10) {
      stage_sw<4>(As[cur ^ 1], A + (size_t)m0 * 640 + (ks + 1) * 64, 640, tid);
      stage_sw<2>(Bs[cur ^ 1], Bw + (size_t)n0 * 640 + (ks + 1) * 64, 640, tid);
    }
#pragma unroll
    for (int h = 0; h < 2; ++h) {
      bf16x8 av[4], bv[2];
#pragma unroll
      for (int f = 0; f < 4; ++f)
        av[f] = rd_sw(As[cur], wm + f * 16 + c, h * 64 + g * 16);
#pragma unroll
      for (int f = 0; f < 2; ++f)
        bv[f] = rd_sw(Bs[cur], wn + f * 16 + c, h * 64 + g * 16);
#pragma unroll
      for (int fm = 0; fm < 4; ++fm)
#pragma unroll
        for (int fn = 0; fn < 2; ++fn)
          acc[fm][fn] = __builtin_amdgcn_mfma_f32_16x16x32_bf16(av[fm], bv[fn], acc[fm][fn], 0, 0, 0);
    }
    __syncthreads();
  }
#pragma unroll
  for (int fm = 0; fm < 4; ++fm)
#pragma unroll
    for (int fn = 0; fn < 2; ++fn)
#pragma unroll
      for (int r = 0; r < 4; ++r) {
        int row = m0 + wm + fm * 16 + g * 4 + r;
        int col = n0 + wn + fn * 16 + c;
        Cout[(size_t)row * 512 + col] = acc[fm][fn][r] + bias[col];
      }
}

// ---------------- attention: 2-slot ring, 32 KB LDS, 4 blocks/CU ----------
// grid (8 qt2, 32 units, 4 b); block owns 128 q-rows; every unit has <=4 kv-tiles.
//  u 0..23 : causal heads 2..7, 4-way split over kv-tiles (kt%4)
//  u 24..27: local heads 0,1, 2-way split (kt parity)
//  u 28..31: ml passes 0,1, 2-way split
__global__ __launch_bounds__(512, 4) void attn_k(
    const u16* __restrict__ P, const u16* __restrict__ Vtb,
    u16* __restrict__ Part_o, float* __restrict__ Part_ml,
    const float* __restrict__ bias_clip, const float* __restrict__ bias_clip_ml) {
  __shared__ u16 Ks[2][4096];   // 2-slot K ring  [k][d]  (swizzled), 8 KB/slot
  __shared__ u16 Vs[2][4096];   // 2-slot V^T ring [d][k] (swizzled), 8 KB/slot
  const int tid = threadIdx.x, lane = tid & 63, w = tid >> 6;
  const int g = lane >> 4, c = lane & 15;
  const int qt2 = blockIdx.x, u = blockIdx.y, b = blockIdx.z;

  int qcol, kcol, vsel;
  bool localMask;
  float kbias;
  unsigned mask;
  unsigned uni = (unsigned)LOC_M[2 * qt2] | (unsigned)LOC_M[2 * qt2 + 1];
  if (u < 24) {
    int h = 2 + (u >> 2), sp = u & 3;
    qcol = h * 64; kcol = 512 + h * 64; vsel = h; kbias = bias_clip[h];
    localMask = false;
    mask = ((unsigned)GLOB_M[2 * qt2] | (unsigned)GLOB_M[2 * qt2 + 1]) & (0x1111u << sp);
  } else if (u < 28) {
    int h = (u - 24) >> 1, sp = (u - 24) & 1;
    qcol = h * 64; kcol = 512 + h * 64; vsel = h; kbias = bias_clip[h];
    localMask = true;
    mask = uni & (sp ? 0xAAAAu : 0x5555u);
  } else {
    int mh = (u - 28) >> 1, sp = (u - 28) & 1;
    qcol = 1024 + mh * 64; kcol = 1152 + mh * 64; vsel = 2 + mh; kbias = bias_clip_ml[mh];
    localMask = true;
    mask = uni & (sp ? 0xAAAAu : 0x5555u);
  }
  kbias *= L2E;   // exp2 domain
  const size_t baseP = (size_t)b * T_SEQ * PW;
  const u16* __restrict__ Kbase = P + baseP + kcol;
  const u16* __restrict__ Vbase = Vtb + ((size_t)b * 512 + vsel * 64) * 1024;
  const int r0 = qt2 * 128 + w * 16;
  const int qg = r0 + c;                     // this lane's q row (global)

  // per-lane visibility bounds (verified R6-R10)
  int tq = (qg < 2) ? 0 : ((qg < 513) ? 2 * qg - 3 : 2 * qg - 1024);
  int upmax = (tq - 1) >> 1;
  int lomax = (tq - 2) >> 1;
  int wmin = (localMask && qg >= 2) ? ((qg < 513 ? qg - 2 : qg - 513) - 3) : -1000000;

  float mM = -1e8f, lL = 0.0f;
  f32x4 o[4] = {};

  if (mask) {
    // Q loads issued FIRST (oldest in vmcnt order)
    bf16x8 aq0 = *(const bf16x8*)&P[baseP + (size_t)qg * PW + qcol + g * 8];
    bf16x8 aq1 = *(const bf16x8*)&P[baseP + (size_t)qg * PW + qcol + 32 + g * 8];

    const int nt = __popc(mask);
    int kts[4] = {0, 0, 0, 0};
    unsigned rem = mask;
#pragma unroll
    for (int j = 0; j < 4; ++j) {
      if (j < nt) { kts[j] = __ffs(rem) - 1; rem &= rem - 1; }
    }
    // prologue: stage tiles 0 and 1 into slots 0,1
    stage8(Ks[0], Kbase + (size_t)(kts[0] * 64) * PW, PW, tid);
    stage8(Vs[0], Vbase + kts[0] * 64, 1024, tid);
    if (nt > 1) {
      stage8(Ks[1], Kbase + (size_t)(kts[1] * 64) * PW, PW, tid);
      stage8(Vs[1], Vbase + kts[1] * 64, 1024, tid);
    }

#pragma unroll
    for (int j = 0; j < 4; ++j) {
      if (j >= nt) break;
      const int sl = j & 1;
      // counted wait: own loads for tile j landed; the one pair beyond stays in flight
      if (j < nt - 1) asm volatile("s_waitcnt vmcnt(2)" ::: "memory");
      else            asm volatile("s_waitcnt vmcnt(0)" ::: "memory");
      __builtin_amdgcn_sched_barrier(0);
      __builtin_amdgcn_s_barrier();          // all waves: slot sl holds tile j

      const int k0 = kts[j] * 64;

      // QK^T swapped (Q pre-scaled): S^T[k][q]; lane (g,c): q=c, k=k0+cb*16+g*4+r
      float s[4][4];
      __builtin_amdgcn_s_setprio(1);
#pragma unroll
      for (int cb = 0; cb < 4; ++cb) {
        f32x4 accs = {};
        bf16x8 bk0 = rd_sw(Ks[sl], cb * 16 + c, g * 16);
        bf16x8 bk1 = rd_sw(Ks[sl], cb * 16 + c, 64 + g * 16);
        accs = __builtin_amdgcn_mfma_f32_16x16x32_bf16(bk0, aq0, accs, 0, 0, 0);
        accs = __builtin_amdgcn_mfma_f32_16x16x32_bf16(bk1, aq1, accs, 0, 0, 0);
#pragma unroll
        for (int r = 0; r < 4; ++r) s[cb][r] = accs[r];
      }
      __builtin_amdgcn_s_setprio(0);

      // mask + clip bias (per-lane scalar bounds, log2 domain)
#pragma unroll
      for (int cb = 0; cb < 4; ++cb) {
        int kb = k0 + cb * 16 + g * 4;
#pragma unroll
        for (int r = 0; r < 4; ++r) {
          int kk = kb + r;
          bool tok = kk < 2;
          bool low = kk >= 513;
          int jk = kk - (low ? 513 : 2);
          int bnd = low ? lomax : upmax;
          bool vis = tok | ((jk <= bnd) & (jk >= wmin));
          float addb = (kk == 1) ? kbias : 0.0f;
          s[cb][r] = vis ? (s[cb][r] + addb) : -1e9f;
        }
      }

      // per-lane online softmax (exp2)
      float rmax = s[0][0];
#pragma unroll
      for (int cb = 0; cb < 4; ++cb)
#pragma unroll
        for (int r = 0; r < 4; ++r) rmax = fmaxf(rmax, s[cb][r]);
      rmax = fmaxf(rmax, __shfl_xor(rmax, 16));
      rmax = fmaxf(rmax, __shfl_xor(rmax, 32));
      float mnew = fmaxf(mM, rmax);
      float fr = exp2f(mM - mnew);
      float psum = 0.0f;
#pragma unroll
      for (int cb = 0; cb < 4; ++cb)
#pragma unroll
        for (int r = 0; r < 4; ++r) {
          float p = exp2f(s[cb][r] - mnew);
          s[cb][r] = p;
          psum += p;
        }
      psum += __shfl_xor(psum, 16);
      psum += __shfl_xor(psum, 32);
      lL = lL * fr + psum;
      mM = mnew;
#pragma unroll
      for (int db = 0; db < 4; ++db) o[db] *= fr;

      // in-register P -> B-fragment redistribution (validated R8-R10)
      unsigned wpk[4][2];
#pragma unroll
      for (int cb = 0; cb < 4; ++cb) {
        asm("v_cvt_pk_bf16_f32 %0, %1, %2" : "=v"(wpk[cb][0]) : "v"(s[cb][0]), "v"(s[cb][1]));
        asm("v_cvt_pk_bf16_f32 %0, %1, %2" : "=v"(wpk[cb][1]) : "v"(s[cb][2]), "v"(s[cb][3]));
      }
#pragma unroll
      for (int ks2 = 0; ks2 < 2; ++ks2) {
        unsigned tw[4];
#pragma unroll
        for (int rr = 0; rr < 2; ++rr) {
          unsigned L = wpk[2 * ks2][rr], H = wpk[2 * ks2 + 1][rr];
          unsigned sA = (g & 1) ? L : H;     // push for xor16 & xor32
          unsigned sB = (g & 1) ? H : L;     // push for xor48
          unsigned X16 = (unsigned)__shfl_xor((int)sA, 16);
          unsigned X32 = (unsigned)__shfl_xor((int)sA, 32);
          unsigned X48 = (unsigned)__shfl_xor((int)sB, 48);
          unsigned a  = (g >= 2) ? ((g == 3) ? X16 : X32) : ((g == 1) ? X48 : L);
          unsigned b2 = (g >= 2) ? ((g == 3) ? H : X48) : ((g == 1) ? X32 : X16);
          tw[rr] = a; tw[2 + rr] = b2;
        }
        u32x4 tw4 = { tw[0], tw[1], tw[2], tw[3] };
        bf16x8 ap = __builtin_bit_cast(bf16x8, tw4);
        __builtin_amdgcn_s_setprio(1);
#pragma unroll
        for (int db = 0; db < 4; ++db) {
          bf16x8 av = rd_sw(Vs[sl], db * 16 + c, ks2 * 64 + g * 16);
          o[db] = __builtin_amdgcn_mfma_f32_16x16x32_bf16(av, ap, o[db], 0, 0, 0);
        }
        __builtin_amdgcn_s_setprio(0);
      }

      __builtin_amdgcn_s_barrier();          // all waves done reading slot sl
      if (j + 2 < nt) {                      // stage tile j+2 into freed slot
        stage8(Ks[sl], Kbase + (size_t)(kts[j + 2] * 64) * PW, PW, tid);
        stage8(Vs[sl], Vbase + kts[j + 2] * 64, 1024, tid);
      }
    }
  }

  // epilogue: lane holds q = qg; o[db][r] = O[q][d = db*16 + g*4 + r]
  u16* po = Part_o + ((size_t)(u * 4 + b)) * T_SEQ * 64;
#pragma unroll
  for (int db = 0; db < 4; ++db) {
    us4 pk = { f2bf(o[db][0]), f2bf(o[db][1]), f2bf(o[db][2]), f2bf(o[db][3]) };
    *(us4*)&po[(size_t)qg * 64 + db * 16 + g * 4] = pk;
  }
  if (g == 0) {
    float2 ml = { mM, lL };
    *(float2*)&Part_ml[(((size_t)(u * 4 + b)) * T_SEQ + qg) * 2] = ml;
  }
}

// combine split partials -> Y (bf16, 640 cols).
__global__ __launch_bounds__(256) void combine_k(
    const u16* __restrict__ Part_o, const float* __restrict__ Part_ml,
    u16* __restrict__ Y, const float* __restrict__ mix_w) {
  int idx = blockIdx.x * 256 + threadIdx.x;  // 10*4*1024*16
  int q4 = idx & 15;
  int row = (idx >> 4) & 1023;
  int bb = (idx >> 14) & 3;
  int j = idx >> 16;
  int ns, bs, outcol;
  float wgt;
  if (j < 6)      { ns = 4; bs = j * 4;            outcol = 128 + j * 64;       wgt = (j < 2) ? mix_w[2 * j] : 1.0f; }
  else if (j < 8) { ns = 2; bs = 24 + (j - 6) * 2; outcol = (j - 6) * 64;       wgt = 1.0f; }
  else            { ns = 2; bs = 28 + (j - 8) * 2; outcol = 512 + (j - 8) * 64; wgt = mix_w[(j - 8) * 2 + 1]; }

  float mv[4], lv[4];
  float ms = -1e30f;
  for (int s = 0; s < ns; ++s) {
    size_t base = (((size_t)(bs + s) * 4 + bb) * 1024 + row) * 2;
    mv[s] = Part_ml[base];
    lv[s] = Part_ml[base + 1];
    ms = fmaxf(ms, mv[s]);
  }
  float denom = 0.0f, e[4];
  for (int s = 0; s < ns; ++s) { e[s] = exp2f(mv[s] - ms); denom += lv[s] * e[s]; }
  float inv = wgt / denom;
  float out[4] = {0.f, 0.f, 0.f, 0.f};
  for (int s = 0; s < ns; ++s) {
    us4 ov = *(const us4*)&Part_o[(((size_t)(bs + s) * 4 + bb) * 1024 + row) * 64 + q4 * 4];
#pragma unroll
    for (int t = 0; t < 4; ++t) out[t] += e[s] * bf2f(ov[t]);
  }
  us4 pk = { f2bf(out[0] * inv), f2bf(out[1] * inv), f2bf(out[2] * inv), f2bf(out[3] * inv) };
  *(us4*)&Y[((size_t)bb * 1024 + row) * 640 + outcol + q4 * 4] = pk;
}

extern "C" void kernel_launch(void* const* d_in, const int* in_sizes, int n_in,
                              void* d_out, int out_size, void* d_ws, size_t ws_size,
                              hipStream_t stream) {
  const float* x     = (const float*)d_in[0];
  const float* Wq    = (const float*)d_in[2];
  const float* bq    = (const float*)d_in[3];
  const float* Wk    = (const float*)d_in[4];
  const float* bk    = (const float*)d_in[5];
  const float* Wv    = (const float*)d_in[6];
  const float* bv    = (const float*)d_in[7];
  const float* Wqml  = (const float*)d_in[8];
  const float* bqml  = (const float*)d_in[9];
  const float* Wkml  = (const float*)d_in[10];
  const float* bkml  = (const float*)d_in[11];
  const float* mixw  = (const float*)d_in[12];
  const float* Wp    = (const float*)d_in[13];
  const float* bp    = (const float*)d_in[14];
  const float* bclip = (const float*)d_in[15];
  const float* bclipml = (const float*)d_in[16];

  u16* xb   = (u16*)d_ws;                  // 4096*512
  u16* Wcat = xb + 4096 * 512;             // 1792*512
  u16* Wpx  = Wcat + 1792 * 512;           // 512*640
  u16* Ybuf = Wpx + 512 * 640;             // 4096*640
  u16* Vtb  = Ybuf + 4096 * 640;           // 4*512*1024
  u16* Pbuf = Vtb + 4 * 512 * 1024;        // 4096*1280
  float* bcat = (float*)(Pbuf + 4096 * 1280);  // 2048 f32
  u16* Part_o = (u16*)(bcat + 2048);       // 32*4*1024*64 bf16 = 16.8 MB
  float* Part_ml = (float*)(Part_o + 32 * 4 * 1024 * 64);  // 32*4*1024*2 f32

  prep_all<<<6919, 256, 0, stream>>>((const float4*)x, xb, Wq, Wk, Wv, Wqml, Wkml, Wp,
                                     bq, bk, bv, bqml, bkml, Wcat, Wpx, bcat);
  gemm_qkv<<<dim3(14, 32), 256, 0, stream>>>(xb, Wcat, bcat, Pbuf, Vtb);
  attn_k<<<dim3(8, 32, 4), 512, 0, stream>>>(Pbuf, Vtb, Part_o, Part_ml, bclip, bclipml);
  combine_k<<<2560, 256, 0, stream>>>(Part_o, Part_ml, Ybuf, mixw);
  gemm_out<<<dim3(8, 32), 256, 0, stream>>>(Ybuf, Wpx, bp, (float*)d_out);
}

// Round 12
// 75.398 us; speedup vs baseline: 1.0295x; 1.0209x over previous
//
#include <hip/hip_runtime.h>

typedef unsigned short u16;
typedef __attribute__((ext_vector_type(8))) __bf16 bf16x8;
typedef __attribute__((ext_vector_type(4))) float f32x4;
typedef __attribute__((ext_vector_type(8))) short short8;
typedef __attribute__((ext_vector_type(4))) u16 us4;
typedef __attribute__((ext_vector_type(4))) unsigned u32x4;

#define T_SEQ 1024
#define PW 1280   // P row: Q(512) K(512) QML(128) KML(128); V lives in Vtb
#define QSC 0.18033688f   // 0.125 * log2(e): folded into Q at projection
#define L2E 1.4426950408889634f

__device__ __forceinline__ u16 f2bf(float f) {
  unsigned u = __float_as_uint(f);
  u += 0x7fff + ((u >> 16) & 1);
  return (u16)(u >> 16);
}
__device__ __forceinline__ float bf2f(u16 v) {
  return __uint_as_float((unsigned)v << 16);
}

// exact per-qtile kv-tile occupancy masks (verified rounds 2-11)
__constant__ u16 GLOB_M[16] = {0x0101,0x0303,0x0707,0x0F0F,0x1F1F,0x3F3F,0x7F7F,0xFFFF,
                               0xFFFF,0x0307,0x070F,0x0F1F,0x1F3F,0x3F7F,0x7FFF,0xFFFF};
__constant__ u16 LOC_M[16]  = {0x0101,0x0303,0x0607,0x0C0D,0x1819,0x3031,0x6061,0xC0C1,
                               0x8183,0x0307,0x060F,0x0C1D,0x1839,0x3071,0x60E1,0xC1C1};

__device__ __forceinline__ void gll16(const u16* gp, u16* lp) {
  __builtin_amdgcn_global_load_lds((const __attribute__((address_space(1))) unsigned*)gp,
                                   (__attribute__((address_space(3))) unsigned*)lp, 16, 0, 0);
}

// 512-thread stage of a 128x64 bf16 tile: linear LDS dest, inv-swizzled src
__device__ __forceinline__ void stage512(u16* lds, const u16* __restrict__ g,
                                         int ld, int tid) {
#pragma unroll
  for (int i = 0; i < 2; ++i) {
    int row = i * 64 + (tid >> 3);
    int cswz = ((tid & 7) << 4) ^ ((row & 7) << 4);
    gll16(g + (size_t)row * ld + (cswz >> 1), lds + i * 4096 + (tid >> 6) * 512);
  }
}

// 256-thread stage: NISS*32 rows x 64 cols
template<int NISS>
__device__ __forceinline__ void stage_sw(u16* lds, const u16* __restrict__ g,
                                         int ld, int tid) {
  const int w = tid >> 6;
#pragma unroll
  for (int i = 0; i < NISS; ++i) {
    int row = i * 32 + (tid >> 3);
    int cswz = ((tid & 7) << 4) ^ ((row & 7) << 4);
    gll16(g + (size_t)row * ld + (cswz >> 1), lds + i * 2048 + w * 512);
  }
}

// 512-thread stage: full 64x64 bf16 tile in ONE gll instr per thread
__device__ __forceinline__ void stage8(u16* lds, const u16* __restrict__ g,
                                       int ld, int tid) {
  int row = tid >> 3;
  int cswz = (((tid & 7) << 4) ^ ((row & 7) << 4)) >> 1;   // u16 units
  gll16(g + (size_t)row * ld + cswz, lds + (tid >> 6) * 512);
}

// read bf16x8 fragment at logical (row, colbyte) from a swizzled 64-col tile
__device__ __forceinline__ bf16x8 rd_sw(const u16* lds, int row, int colbyte) {
  return *(const bf16x8*)&lds[row * 64 + ((colbyte ^ ((row & 7) << 4)) >> 1)];
}

__global__ void prep_all(const float4* __restrict__ x, u16* __restrict__ xb,
                         const float* __restrict__ Wq, const float* __restrict__ Wk,
                         const float* __restrict__ Wv, const float* __restrict__ Wqml,
                         const float* __restrict__ Wkml, const float* __restrict__ Wp,
                         const float* __restrict__ bq, const float* __restrict__ bk,
                         const float* __restrict__ bv, const float* __restrict__ bqml,
                         const float* __restrict__ bkml,
                         u16* __restrict__ Wcat, u16* __restrict__ Wpx, float* __restrict__ bcat) {
  if (blockIdx.x < 2048) {
    int i = blockIdx.x * 256 + threadIdx.x;
    float4 v = x[i];
    us4 o = { f2bf(v.x), f2bf(v.y), f2bf(v.z), f2bf(v.w) };
    *(us4*)&xb[i * 4] = o;
    return;
  }
  int idx = (blockIdx.x - 2048) * 256 + threadIdx.x;
  const int NW = 1792 * 512;
  if (idx < NW) {
    int row = idx >> 9;
    float v;
    if (row < 512)       v = Wq[idx];
    else if (row < 1024) v = Wk[idx - 512 * 512];
    else if (row < 1536) v = Wv[idx - 1024 * 512];
    else if (row < 1664) v = Wqml[idx - 1536 * 512];
    else                 v = Wkml[idx - 1664 * 512];
    Wcat[idx] = f2bf(v);
    return;
  }
  int i2 = idx - NW;
  if (i2 < 512 * 640) {
    int n = i2 / 640, k2 = i2 - n * 640;
    float v = (k2 < 512) ? Wp[n * 512 + k2] : Wp[n * 512 + k2 - 384];
    Wpx[i2] = f2bf(v);
    return;
  }
  int i3 = i2 - 512 * 640;
  if (i3 < 1792) {
    float v;
    if (i3 < 512)       v = bq[i3];
    else if (i3 < 1024) v = bk[i3 - 512];
    else if (i3 < 1536) v = bv[i3 - 1024];
    else if (i3 < 1664) v = bqml[i3 - 1536];
    else                v = bkml[i3 - 1664];
    bcat[i3] = v;
  }
}

// ---------------- 128x128 QKV projection GEMM, BK=64, swizzled, 8 waves --------
// Q and QML output columns pre-scaled by 0.125*log2e (attn works in exp2 domain).
__global__ __launch_bounds__(512) void gemm_qkv(
    const u16* __restrict__ A, const u16* __restrict__ Bw,
    const float* __restrict__ bias, u16* __restrict__ Pout, u16* __restrict__ Vtb) {
  __shared__ u16 As[2][8192];
  __shared__ u16 Bs[2][8192];
  const int tid = threadIdx.x;
  const int lane = tid & 63, w = tid >> 6;
  const int g = lane >> 4, c = lane & 15;
  const int n0 = blockIdx.x * 128, m0 = blockIdx.y * 128;
  const int wm = (w >> 2) * 64, wn = (w & 3) * 32;

  f32x4 acc[4][2] = {};
  stage512(As[0], A + (size_t)m0 * 512, 512, tid);
  stage512(Bs[0], Bw + (size_t)n0 * 512, 512, tid);
  __syncthreads();
  for (int ks = 0; ks < 8; ++ks) {
    int cur = ks & 1;
    if (ks + 1 < 8) {
      stage512(As[cur ^ 1], A + (size_t)m0 * 512 + (ks + 1) * 64, 512, tid);
      stage512(Bs[cur ^ 1], Bw + (size_t)n0 * 512 + (ks + 1) * 64, 512, tid);
    }
#pragma unroll
    for (int h = 0; h < 2; ++h) {
      bf16x8 av[4], bv[2];
#pragma unroll
      for (int f = 0; f < 4; ++f)
        av[f] = rd_sw(As[cur], wm + f * 16 + c, h * 64 + g * 16);
#pragma unroll
      for (int f = 0; f < 2; ++f)
        bv[f] = rd_sw(Bs[cur], wn + f * 16 + c, h * 64 + g * 16);
#pragma unroll
      for (int fm = 0; fm < 4; ++fm)
#pragma unroll
        for (int fn = 0; fn < 2; ++fn)
          acc[fm][fn] = __builtin_amdgcn_mfma_f32_16x16x32_bf16(av[fm], bv[fn], acc[fm][fn], 0, 0, 0);
    }
    __syncthreads();
  }

  const bool isV = (n0 >= 1024 && n0 < 1536);
#pragma unroll
  for (int fm = 0; fm < 4; ++fm)
#pragma unroll
    for (int fn = 0; fn < 2; ++fn) {
      int row = m0 + wm + fm * 16 + g * 4;
      int col = n0 + wn + fn * 16 + c;
      float bb = bias[col];
      if (isV) {
        int d = col - 1024;
        int bidx = row >> 10, t = row & 1023;
        us4 pack = { f2bf(acc[fm][fn][0] + bb), f2bf(acc[fm][fn][1] + bb),
                     f2bf(acc[fm][fn][2] + bb), f2bf(acc[fm][fn][3] + bb) };
        *(us4*)&Vtb[((size_t)bidx * 512 + d) * 1024 + t] = pack;
      } else {
        float sc = (col < 512 || (col >= 1536 && col < 1664)) ? QSC : 1.0f;
        int pcol = (col < 1024) ? col : col - 512;
#pragma unroll
        for (int r = 0; r < 4; ++r)
          Pout[(size_t)(row + r) * PW + pcol] = f2bf((acc[fm][fn][r] + bb) * sc);
      }
    }
}

// ---------------- output projection: 128x64 tiles, K=640, swizzled ----------------
__global__ __launch_bounds__(256) void gemm_out(
    const u16* __restrict__ A, const u16* __restrict__ Bw,
    const float* __restrict__ bias, float* __restrict__ Cout) {
  __shared__ u16 As[2][8192];
  __shared__ u16 Bs[2][4096];
  const int tid = threadIdx.x;
  const int lane = tid & 63, w = tid >> 6;
  const int g = lane >> 4, c = lane & 15;
  const int n0 = blockIdx.x * 64, m0 = blockIdx.y * 128;
  const int wm = (w >> 1) * 64, wn = (w & 1) * 32;

  f32x4 acc[4][2] = {};
  stage_sw<4>(As[0], A + (size_t)m0 * 640, 640, tid);
  stage_sw<2>(Bs[0], Bw + (size_t)n0 * 640, 640, tid);
  __syncthreads();
  for (int ks = 0; ks < 10; ++ks) {
    int cur = ks & 1;
    if (ks + 1 < 10) {
      stage_sw<4>(As[cur ^ 1], A + (size_t)m0 * 640 + (ks + 1) * 64, 640, tid);
      stage_sw<2>(Bs[cur ^ 1], Bw + (size_t)n0 * 640 + (ks + 1) * 64, 640, tid);
    }
#pragma unroll
    for (int h = 0; h < 2; ++h) {
      bf16x8 av[4], bv[2];
#pragma unroll
      for (int f = 0; f < 4; ++f)
        av[f] = rd_sw(As[cur], wm + f * 16 + c, h * 64 + g * 16);
#pragma unroll
      for (int f = 0; f < 2; ++f)
        bv[f] = rd_sw(Bs[cur], wn + f * 16 + c, h * 64 + g * 16);
#pragma unroll
      for (int fm = 0; fm < 4; ++fm)
#pragma unroll
        for (int fn = 0; fn < 2; ++fn)
          acc[fm][fn] = __builtin_amdgcn_mfma_f32_16x16x32_bf16(av[fm], bv[fn], acc[fm][fn], 0, 0, 0);
    }
    __syncthreads();
  }
#pragma unroll
  for (int fm = 0; fm < 4; ++fm)
#pragma unroll
    for (int fn = 0; fn < 2; ++fn)
#pragma unroll
      for (int r = 0; r < 4; ++r) {
        int row = m0 + wm + fm * 16 + g * 4 + r;
        int col = n0 + wn + fn * 16 + c;
        Cout[(size_t)row * 512 + col] = acc[fm][fn][r] + bias[col];
      }
}

// ---------------- attention: fat blocks (<=8 tiles), 2-slot ring ----------
// grid (8 qt2, 16 units, 4 b); block owns 128 q-rows.
//  u 0..11 : causal heads 2..7, 2-way split over kv-tile parity
//  u 12,13 : local heads 0,1 (unsplit)
//  u 14,15 : ml passes 0,1 (unsplit)
// All units write partials; combine_k builds Y.
__global__ __launch_bounds__(512, 4) void attn_k(
    const u16* __restrict__ P, const u16* __restrict__ Vtb,
    u16* __restrict__ Part_o, float* __restrict__ Part_ml,
    const float* __restrict__ bias_clip, const float* __restrict__ bias_clip_ml) {
  __shared__ u16 Ks[2][4096];   // 2-slot K ring  [k][d]  (swizzled), 8 KB/slot
  __shared__ u16 Vs[2][4096];   // 2-slot V^T ring [d][k] (swizzled), 8 KB/slot
  const int tid = threadIdx.x, lane = tid & 63, w = tid >> 6;
  const int g = lane >> 4, c = lane & 15;
  const int qt2 = blockIdx.x, u = blockIdx.y, b = blockIdx.z;

  int qcol, kcol, vsel;
  bool localMask;
  float kbias;
  unsigned mask;
  unsigned uniL = (unsigned)LOC_M[2 * qt2] | (unsigned)LOC_M[2 * qt2 + 1];
  if (u < 12) {
    int h = 2 + (u >> 1), sp = u & 1;
    qcol = h * 64; kcol = 512 + h * 64; vsel = h; kbias = bias_clip[h];
    localMask = false;
    mask = ((unsigned)GLOB_M[2 * qt2] | (unsigned)GLOB_M[2 * qt2 + 1]) & (sp ? 0xAAAAu : 0x5555u);
  } else if (u < 14) {
    int h = u - 12;
    qcol = h * 64; kcol = 512 + h * 64; vsel = h; kbias = bias_clip[h];
    localMask = true;
    mask = uniL;
  } else {
    int mh = u - 14;
    qcol = 1024 + mh * 64; kcol = 1152 + mh * 64; vsel = 2 + mh; kbias = bias_clip_ml[mh];
    localMask = true;
    mask = uniL;
  }
  kbias *= L2E;   // exp2 domain
  const size_t baseP = (size_t)b * T_SEQ * PW;
  const u16* __restrict__ Kbase = P + baseP + kcol;
  const u16* __restrict__ Vbase = Vtb + ((size_t)b * 512 + vsel * 64) * 1024;
  const int r0 = qt2 * 128 + w * 16;
  const int qg = r0 + c;                     // this lane's q row (global)

  // per-lane visibility bounds (verified R6-R11)
  int tq = (qg < 2) ? 0 : ((qg < 513) ? 2 * qg - 3 : 2 * qg - 1024);
  int upmax = (tq - 1) >> 1;
  int lomax = (tq - 2) >> 1;
  int wmin = (localMask && qg >= 2) ? ((qg < 513 ? qg - 2 : qg - 513) - 3) : -1000000;

  float mM = -1e8f, lL = 0.0f;
  f32x4 o[4] = {};

  if (mask) {
    // Q loads issued FIRST (oldest in vmcnt order)
    bf16x8 aq0 = *(const bf16x8*)&P[baseP + (size_t)qg * PW + qcol + g * 8];
    bf16x8 aq1 = *(const bf16x8*)&P[baseP + (size_t)qg * PW + qcol + 32 + g * 8];

    unsigned rem = mask;
    int kt_cur = __ffs(rem) - 1; rem &= rem - 1;
    int kt_n1 = -1;
    stage8(Ks[0], Kbase + (size_t)(kt_cur * 64) * PW, PW, tid);
    stage8(Vs[0], Vbase + kt_cur * 64, 1024, tid);
    if (rem) {
      kt_n1 = __ffs(rem) - 1; rem &= rem - 1;
      stage8(Ks[1], Kbase + (size_t)(kt_n1 * 64) * PW, PW, tid);
      stage8(Vs[1], Vbase + kt_n1 * 64, 1024, tid);
    }
    int sl = 0;

    for (;;) {
      // counted wait: own loads for current tile landed; next pair stays in flight
      if (kt_n1 >= 0) asm volatile("s_waitcnt vmcnt(2)" ::: "memory");
      else            asm volatile("s_waitcnt vmcnt(0)" ::: "memory");
      __builtin_amdgcn_sched_barrier(0);
      __builtin_amdgcn_s_barrier();          // all waves: slot sl holds current tile

      const int k0 = kt_cur * 64;

      // QK^T swapped (Q pre-scaled): S^T[k][q]; lane (g,c): q=c, k=k0+cb*16+g*4+r
      float s[4][4];
      __builtin_amdgcn_s_setprio(1);
#pragma unroll
      for (int cb = 0; cb < 4; ++cb) {
        f32x4 accs = {};
        bf16x8 bk0 = rd_sw(Ks[sl], cb * 16 + c, g * 16);
        bf16x8 bk1 = rd_sw(Ks[sl], cb * 16 + c, 64 + g * 16);
        accs = __builtin_amdgcn_mfma_f32_16x16x32_bf16(bk0, aq0, accs, 0, 0, 0);
        accs = __builtin_amdgcn_mfma_f32_16x16x32_bf16(bk1, aq1, accs, 0, 0, 0);
#pragma unroll
        for (int r = 0; r < 4; ++r) s[cb][r] = accs[r];
      }
      __builtin_amdgcn_s_setprio(0);

      // mask + clip bias (per-lane scalar bounds, log2 domain)
#pragma unroll
      for (int cb = 0; cb < 4; ++cb) {
        int kb = k0 + cb * 16 + g * 4;
#pragma unroll
        for (int r = 0; r < 4; ++r) {
          int kk = kb + r;
          bool tok = kk < 2;
          bool low = kk >= 513;
          int jk = kk - (low ? 513 : 2);
          int bnd = low ? lomax : upmax;
          bool vis = tok | ((jk <= bnd) & (jk >= wmin));
          float addb = (kk == 1) ? kbias : 0.0f;
          s[cb][r] = vis ? (s[cb][r] + addb) : -1e9f;
        }
      }

      // per-lane online softmax (exp2)
      float rmax = s[0][0];
#pragma unroll
      for (int cb = 0; cb < 4; ++cb)
#pragma unroll
        for (int r = 0; r < 4; ++r) rmax = fmaxf(rmax, s[cb][r]);
      rmax = fmaxf(rmax, __shfl_xor(rmax, 16));
      rmax = fmaxf(rmax, __shfl_xor(rmax, 32));
      float mnew = fmaxf(mM, rmax);
      float fr = exp2f(mM - mnew);
      float psum = 0.0f;
#pragma unroll
      for (int cb = 0; cb < 4; ++cb)
#pragma unroll
        for (int r = 0; r < 4; ++r) {
          float p = exp2f(s[cb][r] - mnew);
          s[cb][r] = p;
          psum += p;
        }
      psum += __shfl_xor(psum, 16);
      psum += __shfl_xor(psum, 32);
      lL = lL * fr + psum;
      mM = mnew;
#pragma unroll
      for (int db = 0; db < 4; ++db) o[db] *= fr;

      // in-register P -> B-fragment redistribution (validated R8-R11)
      unsigned wpk[4][2];
#pragma unroll
      for (int cb = 0; cb < 4; ++cb) {
        asm("v_cvt_pk_bf16_f32 %0, %1, %2" : "=v"(wpk[cb][0]) : "v"(s[cb][0]), "v"(s[cb][1]));
        asm("v_cvt_pk_bf16_f32 %0, %1, %2" : "=v"(wpk[cb][1]) : "v"(s[cb][2]), "v"(s[cb][3]));
      }
#pragma unroll
      for (int ks2 = 0; ks2 < 2; ++ks2) {
        unsigned tw[4];
#pragma unroll
        for (int rr = 0; rr < 2; ++rr) {
          unsigned L = wpk[2 * ks2][rr], H = wpk[2 * ks2 + 1][rr];
          unsigned sA = (g & 1) ? L : H;     // push for xor16 & xor32
          unsigned sB = (g & 1) ? H : L;     // push for xor48
          unsigned X16 = (unsigned)__shfl_xor((int)sA, 16);
          unsigned X32 = (unsigned)__shfl_xor((int)sA, 32);
          unsigned X48 = (unsigned)__shfl_xor((int)sB, 48);
          unsigned a  = (g >= 2) ? ((g == 3) ? X16 : X32) : ((g == 1) ? X48 : L);
          unsigned b2 = (g >= 2) ? ((g == 3) ? H : X48) : ((g == 1) ? X32 : X16);
          tw[rr] = a; tw[2 + rr] = b2;
        }
        u32x4 tw4 = { tw[0], tw[1], tw[2], tw[3] };
        bf16x8 ap = __builtin_bit_cast(bf16x8, tw4);
        __builtin_amdgcn_s_setprio(1);
#pragma unroll
        for (int db = 0; db < 4; ++db) {
          bf16x8 av = rd_sw(Vs[sl], db * 16 + c, ks2 * 64 + g * 16);
          o[db] = __builtin_amdgcn_mfma_f32_16x16x32_bf16(av, ap, o[db], 0, 0, 0);
        }
        __builtin_amdgcn_s_setprio(0);
      }

      __builtin_amdgcn_s_barrier();          // all waves done reading slot sl
      int kt_n2 = -1;
      if (rem) {
        kt_n2 = __ffs(rem) - 1; rem &= rem - 1;
        stage8(Ks[sl], Kbase + (size_t)(kt_n2 * 64) * PW, PW, tid);
        stage8(Vs[sl], Vbase + kt_n2 * 64, 1024, tid);
      }
      if (kt_n1 < 0) break;
      kt_cur = kt_n1; kt_n1 = kt_n2; sl ^= 1;
    }
  }

  // epilogue: lane holds q = qg; o[db][r] = O[q][d = db*16 + g*4 + r]
  u16* po = Part_o + ((size_t)(u * 4 + b)) * T_SEQ * 64;
#pragma unroll
  for (int db = 0; db < 4; ++db) {
    us4 pk = { f2bf(o[db][0]), f2bf(o[db][1]), f2bf(o[db][2]), f2bf(o[db][3]) };
    *(us4*)&po[(size_t)qg * 64 + db * 16 + g * 4] = pk;
  }
  if (g == 0) {
    float2 ml = { mM, lL };
    *(float2*)&Part_ml[(((size_t)(u * 4 + b)) * T_SEQ + qg) * 2] = ml;
  }
}

// combine split partials -> Y (bf16, 640 cols).
// j 0..5: causal head 2+j (slots 2j, 2j+1, ns=2) -> cols 128+64j
// j 6..7: local head j-6 (slot 12+(j-6), ns=1)   -> cols 64(j-6)
// j 8..9: ml (j-8)       (slot 14+(j-8), ns=1)   -> cols 512+64(j-8)
__global__ __launch_bounds__(256) void combine_k(
    const u16* __restrict__ Part_o, const float* __restrict__ Part_ml,
    u16* __restrict__ Y, const float* __restrict__ mix_w) {
  int idx = blockIdx.x * 256 + threadIdx.x;  // 10*4*1024*16
  int q4 = idx & 15;
  int row = (idx >> 4) & 1023;
  int bb = (idx >> 14) & 3;
  int j = idx >> 16;
  int ns, bs, outcol;
  float wgt;
  if (j < 6)      { ns = 2; bs = j * 2;       outcol = 128 + j * 64;       wgt = (j < 2) ? mix_w[2 * j] : 1.0f; }
  else if (j < 8) { ns = 1; bs = 12 + (j - 6); outcol = (j - 6) * 64;       wgt = 1.0f; }
  else            { ns = 1; bs = 14 + (j - 8); outcol = 512 + (j - 8) * 64; wgt = mix_w[(j - 8) * 2 + 1]; }

  float mv[2], lv[2];
  float ms = -1e30f;
  for (int s = 0; s < ns; ++s) {
    size_t base = (((size_t)(bs + s) * 4 + bb) * 1024 + row) * 2;
    mv[s] = Part_ml[base];
    lv[s] = Part_ml[base + 1];
    ms = fmaxf(ms, mv[s]);
  }
  float denom = 0.0f, e[2];
  for (int s = 0; s < ns; ++s) { e[s] = exp2f(mv[s] - ms); denom += lv[s] * e[s]; }
  float inv = wgt / denom;
  float out[4] = {0.f, 0.f, 0.f, 0.f};
  for (int s = 0; s < ns; ++s) {
    us4 ov = *(const us4*)&Part_o[(((size_t)(bs + s) * 4 + bb) * 1024 + row) * 64 + q4 * 4];
#pragma unroll
    for (int t = 0; t < 4; ++t) out[t] += e[s] * bf2f(ov[t]);
  }
  us4 pk = { f2bf(out[0] * inv), f2bf(out[1] * inv), f2bf(out[2] * inv), f2bf(out[3] * inv) };
  *(us4*)&Y[((size_t)bb * 1024 + row) * 640 + outcol + q4 * 4] = pk;
}

extern "C" void kernel_launch(void* const* d_in, const int* in_sizes, int n_in,
                              void* d_out, int out_size, void* d_ws, size_t ws_size,
                              hipStream_t stream) {
  const float* x     = (const float*)d_in[0];
  const float* Wq    = (const float*)d_in[2];
  const float* bq    = (const float*)d_in[3];
  const float* Wk    = (const float*)d_in[4];
  const float* bk    = (const float*)d_in[5];
  const float* Wv    = (const float*)d_in[6];
  const float* bv    = (const float*)d_in[7];
  const float* Wqml  = (const float*)d_in[8];
  const float* bqml  = (const float*)d_in[9];
  const float* Wkml  = (const float*)d_in[10];
  const float* bkml  = (const float*)d_in[11];
  const float* mixw  = (const float*)d_in[12];
  const float* Wp    = (const float*)d_in[13];
  const float* bp    = (const float*)d_in[14];
  const float* bclip = (const float*)d_in[15];
  const float* bclipml = (const float*)d_in[16];

  u16* xb   = (u16*)d_ws;                  // 4096*512
  u16* Wcat = xb + 4096 * 512;             // 1792*512
  u16* Wpx  = Wcat + 1792 * 512;           // 512*640
  u16* Ybuf = Wpx + 512 * 640;             // 4096*640
  u16* Vtb  = Ybuf + 4096 * 640;           // 4*512*1024
  u16* Pbuf = Vtb + 4 * 512 * 1024;        // 4096*1280
  float* bcat = (float*)(Pbuf + 4096 * 1280);  // 2048 f32
  u16* Part_o = (u16*)(bcat + 2048);       // 16*4*1024*64 bf16 = 8.4 MB
  float* Part_ml = (float*)(Part_o + 16 * 4 * 1024 * 64);  // 16*4*1024*2 f32

  prep_all<<<6919, 256, 0, stream>>>((const float4*)x, xb, Wq, Wk, Wv, Wqml, Wkml, Wp,
                                     bq, bk, bv, bqml, bkml, Wcat, Wpx, bcat);
  gemm_qkv<<<dim3(14, 32), 512, 0, stream>>>(xb, Wcat, bcat, Pbuf, Vtb);
  attn_k<<<dim3(8, 16, 4), 512, 0, stream>>>(Pbuf, Vtb, Part_o, Part_ml, bclip, bclipml);
  combine_k<<<2560, 256, 0, stream>>>(Part_o, Part_ml, Ybuf, mixw);
  gemm_out<<<dim3(8, 32), 256, 0, stream>>>(Ybuf, Wpx, bp, (float*)d_out);
}